// Round 1
// baseline (2563.352 us; speedup 1.0000x reference)
//
#include <hip/hip_runtime.h>

#define NN 2048
#define BB 8
#define NITER 50
#define RCHUNKS 16
#define ROWS_PER_CHUNK (NN / RCHUNKS)   // 128

__device__ __forceinline__ float eps_f()      { return 0.01f; }
__device__ __forceinline__ float inv_eps_f()  { return 100.0f; }
// 0.01f * (-logf(2048.f)) = -0.0762461898616f
__device__ __forceinline__ float eps_logmu_f(){ return -0.0762461898616f; }

// combine two (max, sum-of-exp-relative-to-max) pairs in x-space
// (LSE argument is x * 100, so exponent deltas are scaled by INV_EPS)
__device__ __forceinline__ void lse_combine(float& m, float& s, float om, float os) {
    float M = fmaxf(m, om);
    s = s * __expf((m - M) * inv_eps_f()) + os * __expf((om - M) * inv_eps_f());
    m = M;
}

// ---------------- init: zero u, v ----------------
__global__ __launch_bounds__(256) void k_init(float* __restrict__ u, float* __restrict__ v) {
    int idx = blockIdx.x * 256 + threadIdx.x;
    if (idx < BB * NN) { u[idx] = 0.0f; v[idx] = 0.0f; }
}

// ---------------- u update: one block per (b,i) row ----------------
// u[b,i] = eps*log_mu - max_j(c+v) - eps*log( sum_j exp((c+v - max)*100) )
__global__ __launch_bounds__(256) void k_u(const float* __restrict__ c,
                                           const float* __restrict__ v,
                                           float* __restrict__ u) {
    int row = blockIdx.x;            // b*NN + i
    int b   = row >> 11;
    int t   = threadIdx.x;
    const float4* crow = (const float4*)(c + (size_t)row * NN);
    const float4* vb   = (const float4*)(v + (size_t)b * NN);

    float4 c0 = crow[t];
    float4 c1 = crow[t + 256];
    float4 v0 = vb[t];
    float4 v1 = vb[t + 256];

    float x[8] = { c0.x + v0.x, c0.y + v0.y, c0.z + v0.z, c0.w + v0.w,
                   c1.x + v1.x, c1.y + v1.y, c1.z + v1.z, c1.w + v1.w };

    float m = x[0];
#pragma unroll
    for (int k = 1; k < 8; ++k) m = fmaxf(m, x[k]);
    float s = 0.0f;
#pragma unroll
    for (int k = 0; k < 8; ++k) s += __expf((x[k] - m) * inv_eps_f());

    // wave (64-lane) butterfly reduction of (m, s)
#pragma unroll
    for (int off = 32; off; off >>= 1) {
        float om = __shfl_xor(m, off, 64);
        float os = __shfl_xor(s, off, 64);
        lse_combine(m, s, om, os);
    }
    __shared__ float sm[4], ss[4];
    int wid = t >> 6;
    if ((t & 63) == 0) { sm[wid] = m; ss[wid] = s; }
    __syncthreads();
    if (t == 0) {
#pragma unroll
        for (int w = 1; w < 4; ++w) lse_combine(m, s, sm[w], ss[w]);
        u[row] = eps_logmu_f() - m - eps_f() * __logf(s);
    }
}

// ---------------- v update, phase 1: partial column LSE ----------------
// grid: (NN/256 col-groups, RCHUNKS row-chunks, BB)
__global__ __launch_bounds__(256) void k_v_partial(const float* __restrict__ c,
                                                   const float* __restrict__ u,
                                                   float* __restrict__ pm,
                                                   float* __restrict__ ps) {
    int j     = blockIdx.x * 256 + threadIdx.x;
    int chunk = blockIdx.y;
    int b     = blockIdx.z;
    const float* cb = c + (size_t)b * NN * NN;
    const float* ub = u + (size_t)b * NN;

    int i0 = chunk * ROWS_PER_CHUNK;
    float m = -INFINITY, s = 0.0f;
    for (int i = i0; i < i0 + ROWS_PER_CHUNK; i += 4) {
        float u0 = ub[i], u1 = ub[i + 1], u2 = ub[i + 2], u3 = ub[i + 3];
        float x0 = cb[(size_t)(i + 0) * NN + j] + u0;
        float x1 = cb[(size_t)(i + 1) * NN + j] + u1;
        float x2 = cb[(size_t)(i + 2) * NN + j] + u2;
        float x3 = cb[(size_t)(i + 3) * NN + j] + u3;
        float lm = fmaxf(fmaxf(x0, x1), fmaxf(x2, x3));
        float ls = __expf((x0 - lm) * inv_eps_f()) + __expf((x1 - lm) * inv_eps_f())
                 + __expf((x2 - lm) * inv_eps_f()) + __expf((x3 - lm) * inv_eps_f());
        lse_combine(m, s, lm, ls);
    }
    int o = (b * RCHUNKS + chunk) * NN + j;
    pm[o] = m;
    ps[o] = s;
}

// ---------------- v update, phase 2: combine partials ----------------
__global__ __launch_bounds__(256) void k_v_combine(const float* __restrict__ pm,
                                                   const float* __restrict__ ps,
                                                   float* __restrict__ v) {
    int idx = blockIdx.x * 256 + threadIdx.x;   // b*NN + j
    int b = idx >> 11;
    int j = idx & (NN - 1);
    float m = -INFINITY, s = 0.0f;
#pragma unroll
    for (int r = 0; r < RCHUNKS; ++r) {
        int o = (b * RCHUNKS + r) * NN + j;
        lse_combine(m, s, pm[o], ps[o]);
    }
    float val = eps_logmu_f() - m - eps_f() * __logf(s);
    if (val > 9e8f) val = 0.0f;   // reference's huge-value clamp (never fires in practice)
    v[idx] = val;
}

// ---------------- finalize: pi = exp((c+u+v)*100), negc = -c ----------------
__global__ __launch_bounds__(256) void k_final(const float* __restrict__ c,
                                               const float* __restrict__ u,
                                               const float* __restrict__ v,
                                               float* __restrict__ pi,
                                               float* __restrict__ negc) {
    unsigned q = blockIdx.x * 256 + threadIdx.x;     // float4 index
    unsigned e = q * 4;                               // element index
    unsigned b = e >> 22;                             // / (NN*NN)
    unsigned rem = e & (NN * NN - 1);
    unsigned i = rem >> 11;
    unsigned j = rem & (NN - 1);

    float4 cc = ((const float4*)c)[q];
    float ui = u[b * NN + i];
    const float* vp = v + b * NN + j;
    float4 vv = *(const float4*)vp;

    float4 p;
    p.x = __expf((cc.x + ui + vv.x) * inv_eps_f());
    p.y = __expf((cc.y + ui + vv.y) * inv_eps_f());
    p.z = __expf((cc.z + ui + vv.z) * inv_eps_f());
    p.w = __expf((cc.w + ui + vv.w) * inv_eps_f());
    ((float4*)pi)[q] = p;

    float4 nc = { -cc.x, -cc.y, -cc.z, -cc.w };
    ((float4*)negc)[q] = nc;
}

// ---------------- copy u, v to output ----------------
__global__ __launch_bounds__(256) void k_uv_out(const float* __restrict__ u,
                                                const float* __restrict__ v,
                                                float* __restrict__ ou,
                                                float* __restrict__ ov) {
    int idx = blockIdx.x * 256 + threadIdx.x;
    if (idx < BB * NN) { ou[idx] = u[idx]; ov[idx] = v[idx]; }
}

extern "C" void kernel_launch(void* const* d_in, const int* in_sizes, int n_in,
                              void* d_out, int out_size, void* d_ws, size_t ws_size,
                              hipStream_t stream) {
    const float* c = (const float*)d_in[0];
    float* out  = (float*)d_out;
    float* pi   = out;
    float* negc = out + (size_t)BB * NN * NN;
    float* ou   = out + 2 * (size_t)BB * NN * NN;
    float* ov   = ou + BB * NN;

    float* ws = (float*)d_ws;
    float* u  = ws;
    float* v  = ws + BB * NN;
    float* pm = ws + 2 * BB * NN;
    float* ps = pm + BB * RCHUNKS * NN;

    k_init<<<(BB * NN) / 256, 256, 0, stream>>>(u, v);

    dim3 gB(NN / 256, RCHUNKS, BB);
    for (int it = 0; it < NITER; ++it) {
        k_u<<<BB * NN, 256, 0, stream>>>(c, v, u);
        k_v_partial<<<gB, 256, 0, stream>>>(c, u, pm, ps);
        k_v_combine<<<(BB * NN) / 256, 256, 0, stream>>>(pm, ps, v);
    }

    unsigned n4 = (unsigned)((size_t)BB * NN * NN / 4);
    k_final<<<n4 / 256, 256, 0, stream>>>(c, u, v, pi, negc);
    k_uv_out<<<(BB * NN) / 256, 256, 0, stream>>>(u, v, ou, ov);
}